// Round 3
// baseline (184.607 us; speedup 1.0000x reference)
//
#include <hip/hip_runtime.h>
#include <math.h>
#include <stdint.h>

#define BB 4
#define NN 1024
#define HH 8
#define DD 64
#define BS 32
#define NB 32   // NN/BS
#define SS 16   // BLOCK_COUNTS

typedef __attribute__((ext_vector_type(8)))  short bf16x8;
typedef __attribute__((ext_vector_type(16))) float f32x16;
typedef __attribute__((ext_vector_type(2)))  int   int2v;

union FragU { bf16x8 h; uint32_t u[4]; };

#define ZERO16 {0.f,0.f,0.f,0.f,0.f,0.f,0.f,0.f,0.f,0.f,0.f,0.f,0.f,0.f,0.f,0.f}

__device__ __forceinline__ uint32_t cvt_pk_bf16(float lo, float hi) {
    uint32_t r;
    asm("v_cvt_pk_bf16_f32 %0, %1, %2" : "=v"(r) : "v"(lo), "v"(hi));
    return r;
}

__device__ __forceinline__ float silu_f(float x) {
    return __fdividef(x, 1.f + __expf(-x));
}

// Block-mean compressed K/V: kc/vc layout [B][NB][H][D] (f32).
// One wave per (b,blk,h); float4 loads; shfl reduce over 4 row-groups.
__global__ __launch_bounds__(256) void cmp_mean_kernel(
    const float* __restrict__ pk, const float* __restrict__ pv,
    float* __restrict__ kc, float* __restrict__ vc)
{
    int w = threadIdx.x >> 6;
    int lane = threadIdx.x & 63;
    int idx = blockIdx.x * 4 + w;            // ((b*NB)+blk)*HH + h
    int r0 = lane >> 4;                      // row group 0..3
    int c4 = (lane & 15) << 2;               // d start (float4)
    int h = idx & 7, blk = (idx >> 3) & 31, b = idx >> 8;
    size_t base = (((size_t)(b * NN + blk * BS + r0)) * HH + h) * DD + c4;
    float k0=0,k1=0,k2=0,k3=0,v0=0,v1=0,v2=0,v3=0;
    #pragma unroll
    for (int j = 0; j < 8; ++j) {
        const float* kp = pk + base + (size_t)j * 4 * HH * DD;  // rows r0+4j
        const float* vp = pv + base + (size_t)j * 4 * HH * DD;
        float4 a = *(const float4*)kp;
        float4 c = *(const float4*)vp;
        k0+=a.x; k1+=a.y; k2+=a.z; k3+=a.w;
        v0+=c.x; v1+=c.y; v2+=c.z; v3+=c.w;
    }
    #pragma unroll
    for (int off = 16; off < 64; off <<= 1) {
        k0 += __shfl_xor(k0, off); k1 += __shfl_xor(k1, off);
        k2 += __shfl_xor(k2, off); k3 += __shfl_xor(k3, off);
        v0 += __shfl_xor(v0, off); v1 += __shfl_xor(v1, off);
        v2 += __shfl_xor(v2, off); v3 += __shfl_xor(v3, off);
    }
    if (lane < 16) {
        const float sc = 1.f / BS;
        *(float4*)(kc + (size_t)idx * DD + c4) = make_float4(k0*sc, k1*sc, k2*sc, k3*sc);
        *(float4*)(vc + (size_t)idx * DD + c4) = make_float4(v0*sc, v1*sc, v2*sc, v3*sc);
    }
}

// One workgroup (4 waves) per (b, h, q_block) tile of 32 queries.
__global__ __launch_bounds__(256, 4) void bsa_mfma_kernel(
    const float* __restrict__ pq, const float* __restrict__ pk,
    const float* __restrict__ pv, const float* __restrict__ kc,
    const float* __restrict__ vc, const float* __restrict__ gw,
    const int* __restrict__ xoff, float* __restrict__ out)
{
    __shared__ float qlds[32][64];                       // 8 KB
    __shared__ __align__(16) uint16_t pcmp[32][40];      // 2.5 KB, bf16, padded stride
    __shared__ uint32_t selmask[32];
    __shared__ float gateC[32], gateS[32];
    __shared__ float olds[32][64];                       // 8 KB, gated accumulation slab

    const int tid = threadIdx.x;
    const int lane = tid & 63;
    const int w = tid >> 6;
    const int l31 = lane & 31;
    const int hi = lane >> 5;

    // balanced mapping: CU-mates (bid +256k) get staggered qb
    const int bid = blockIdx.x;
    const int qi = bid & 31;
    const int bh = bid >> 5;                 // 0..31 = b*8+h
    const int qb = (qi + bh) & 31;
    const int h = bh & 7;
    const int b = bh >> 3;

    const int off0 = xoff[b];
    const int len = xoff[b + 1] - off0;
    if (qb * BS >= len) return;              // fully-padded tile (uniform)

    // ---- zero accumulation slab ----
    {
        int q = tid >> 3, d = (tid & 7) * 8;
        *(float4*)&olds[q][d] = make_float4(0.f, 0.f, 0.f, 0.f);
        *(float4*)&olds[q][d + 4] = make_float4(0.f, 0.f, 0.f, 0.f);
    }

    // ---- cooperative load of Q tile (f32) for selection/gates ----
    {
        int q = tid >> 3, part = (tid & 7) * 8;
        const float* src = pq + (((size_t)(b * NN + qb * BS + q)) * HH + h) * DD + part;
        *(float4*)&qlds[q][part] = *(const float4*)src;
        *(float4*)&qlds[q][part + 4] = *(const float4*)(src + 4);
    }

    // ---- Q B-fragments (bf16) direct from global: lane = query l31 ----
    FragU qf[4];
    {
        const float* qrow = pq + (((size_t)(b * NN + qb * BS + l31)) * HH + h) * DD;
        #pragma unroll
        for (int t = 0; t < 4; ++t) {
            const float* qp = qrow + t * 16 + hi * 8;
            float4 x = *(const float4*)qp;
            float4 y = *(const float4*)(qp + 4);
            qf[t].u[0] = cvt_pk_bf16(x.x, x.y);
            qf[t].u[1] = cvt_pk_bf16(x.z, x.w);
            qf[t].u[2] = cvt_pk_bf16(y.x, y.y);
            qf[t].u[3] = cvt_pk_bf16(y.z, y.w);
        }
    }

    // ---- compressed-K fragment for selection dots: lane = (blk=l31, half=hi) ----
    float4 kcv[8];
    {
        const float* kcrow = kc + (((size_t)(b * NB + l31)) * HH + h) * DD + hi * 32;
        #pragma unroll
        for (int i = 0; i < 8; ++i) kcv[i] = *(const float4*)(kcrow + i * 4);
    }

    __syncthreads();   // qlds + olds ready

    // ---- selection + gates: wave w handles queries w*8 .. w*8+7 ----
    for (int j = 0; j < 8; ++j) {
        int q = w * 8 + j;
        const float* qv = qlds[q];
        const float* qh = qv + hi * 32;
        float part = 0.f;
        #pragma unroll
        for (int i = 0; i < 8; ++i) {
            float4 qq = *(const float4*)(qh + i * 4);
            part += qq.x * kcv[i].x + qq.y * kcv[i].y + qq.z * kcv[i].z + qq.w * kcv[i].w;
        }
        float s = (part + __shfl_xor(part, 32)) * 0.125f;
        float p = (l31 <= qb) ? silu_f(s) : 0.f;
        if (lane < 32) {                                  // bf16 RNE store of p_cmp
            uint32_t fb = __float_as_uint(p);
            uint16_t bp = (uint16_t)((fb + 0x7fffu + ((fb >> 16) & 1u)) >> 16);
            pcmp[q][l31] = bp;
        }
        // top-16 mask (fp32 scores, index tie-break == jax.lax.top_k)
        uint32_t m;
        if (qb >= SS) {
            float vsel = (l31 <= qb) ? s : -INFINITY;
            int rank = 0;
            #pragma unroll
            for (int off = 1; off < 32; ++off) {
                float o = __shfl_xor(vsel, off);
                int oi = l31 ^ off;
                rank += (o > vsel || (o == vsel && oi < l31)) ? 1 : 0;
            }
            m = (uint32_t)(__ballot(rank < SS) & 0xffffffffu);
        } else {
            m = (1u << (qb + 1)) - 1u;
        }
        if (lane == 0) selmask[q] = m;
        // gates
        float qd = qv[lane];
        float g0 = qd * gw[(h * DD + lane) * 3 + 0];
        float g1 = qd * gw[(h * DD + lane) * 3 + 1];
        #pragma unroll
        for (int off = 32; off; off >>= 1) {
            g0 += __shfl_xor(g0, off);
            g1 += __shfl_xor(g1, off);
        }
        if (lane == 0) {
            gateC[q] = __frcp_rn(1.f + __expf(-g0));
            gateS[q] = __frcp_rn(1.f + __expf(-g1));
        }
    }

    __syncthreads();   // pcmp, selmask, gates ready

    const uint32_t mymask = selmask[l31];   // per-lane: mask for query l31
    uint32_t tmask = mymask;                 // tile union of selected blocks
    #pragma unroll
    for (int off = 1; off < 32; off <<= 1) tmask |= __shfl_xor(tmask, off);

    // ---- wave 3: compressed branch o_cmp = P_cmp · v_cmp via MFMA (gated) ----
    if (w == 3) {
        f32x16 c0 = ZERO16, c1 = ZERO16;
        #pragma unroll
        for (int s = 0; s < 2; ++s) {
            FragU pa;
            pa.h = *(const bf16x8*)&pcmp[l31][s * 16 + hi * 8];
            const float* vbase = vc + (((size_t)(b * NB + s * 16 + hi * 8)) * HH + h) * DD + l31;
            #pragma unroll
            for (int dh = 0; dh < 2; ++dh) {
                FragU vb;
                #pragma unroll
                for (int jj = 0; jj < 4; ++jj) {
                    float a = vbase[(2 * jj) * 512 + dh * 32];
                    float c = vbase[(2 * jj + 1) * 512 + dh * 32];
                    vb.u[jj] = cvt_pk_bf16(a, c);
                }
                if (dh == 0) c0 = __builtin_amdgcn_mfma_f32_32x32x16_bf16(pa.h, vb.h, c0, 0, 0, 0);
                else         c1 = __builtin_amdgcn_mfma_f32_32x32x16_bf16(pa.h, vb.h, c1, 0, 0, 0);
            }
        }
        #pragma unroll
        for (int r = 0; r < 16; ++r) {
            int q = (r & 3) + 8 * (r >> 2) + 4 * hi;
            float gc = gateC[q];
            atomicAdd(&olds[q][l31], gc * c0[r]);
            atomicAdd(&olds[q][32 + l31], gc * c1[r]);
        }
    }

    // ---- main loop: waves round-robin over union-selected key blocks ----
    f32x16 accO0 = ZERO16, accO1 = ZERO16;
    bool any = false;
    const int qpos = qb * BS + l31;
    {
        uint32_t m = tmask;
        int bcnt = 0;
        while (m) {
            int kb = __builtin_ctz(m); m &= m - 1;
            if (((bcnt++) & 3) != w) continue;
            any = true;
            // S^T = K_blk · Q^T  (4 mfma over d)
            f32x16 accS = ZERO16;
            const float* krow = pk + (((size_t)(b * NN + kb * BS + l31)) * HH + h) * DD;
            #pragma unroll
            for (int t = 0; t < 4; ++t) {
                const float* kp = krow + t * 16 + hi * 8;
                float4 x = *(const float4*)kp;
                float4 y = *(const float4*)(kp + 4);
                FragU kf;
                kf.u[0] = cvt_pk_bf16(x.x, x.y);
                kf.u[1] = cvt_pk_bf16(x.z, x.w);
                kf.u[2] = cvt_pk_bf16(y.x, y.y);
                kf.u[3] = cvt_pk_bf16(y.z, y.w);
                accS = __builtin_amdgcn_mfma_f32_32x32x16_bf16(kf.h, qf[t].h, accS, 0, 0, 0);
            }
            // mask + silu (lane holds q = l31; rows are keys)
            const bool selbit = (mymask >> kb) & 1;
            const bool notdiag = kb < qb;
            float pr[16];
            #pragma unroll
            for (int r = 0; r < 16; ++r) {
                int key = (r & 3) + 8 * (r >> 2) + 4 * hi;
                int kpos = kb * BS + key;
                float s = accS[r] * 0.125f;
                bool ok = selbit && (notdiag || kpos <= qpos);
                pr[r] = ok ? silu_f(s) : 0.f;
            }
            // P -> A-operand layout: cvt_pk pairs + permlane32 swaps
            uint32_t wv[8];
            #pragma unroll
            for (int i = 0; i < 8; ++i) wv[i] = cvt_pk_bf16(pr[2 * i], pr[2 * i + 1]);
            int2v e0 = __builtin_amdgcn_permlane32_swap(wv[0], wv[2], false, false);
            int2v e1 = __builtin_amdgcn_permlane32_swap(wv[1], wv[3], false, false);
            int2v e2 = __builtin_amdgcn_permlane32_swap(wv[4], wv[6], false, false);
            int2v e3 = __builtin_amdgcn_permlane32_swap(wv[5], wv[7], false, false);
            FragU a0, a1;
            a0.u[0] = e0[0]; a0.u[1] = e1[0]; a0.u[2] = e0[1]; a0.u[3] = e1[1];
            a1.u[0] = e2[0]; a1.u[1] = e3[0]; a1.u[2] = e2[1]; a1.u[3] = e3[1];
            // PV: O += P · V (V fragments direct from global, f32 -> bf16)
            #pragma unroll
            for (int s = 0; s < 2; ++s) {
                const float* vbase = pv + (((size_t)(b * NN + kb * BS + s * 16 + hi * 8)) * HH + h) * DD + l31;
                const FragU& pa = s ? a1 : a0;
                #pragma unroll
                for (int dh = 0; dh < 2; ++dh) {
                    FragU vb;
                    #pragma unroll
                    for (int jj = 0; jj < 4; ++jj) {
                        float a = vbase[(2 * jj) * 512 + dh * 32];
                        float c = vbase[(2 * jj + 1) * 512 + dh * 32];
                        vb.u[jj] = cvt_pk_bf16(a, c);
                    }
                    if (dh == 0) accO0 = __builtin_amdgcn_mfma_f32_32x32x16_bf16(pa.h, vb.h, accO0, 0, 0, 0);
                    else         accO1 = __builtin_amdgcn_mfma_f32_32x32x16_bf16(pa.h, vb.h, accO1, 0, 0, 0);
                }
            }
        }
    }

    // ---- gated accumulation of selected-branch partials ----
    if (any) {
        #pragma unroll
        for (int r = 0; r < 16; ++r) {
            int q = (r & 3) + 8 * (r >> 2) + 4 * hi;
            float gs = gateS[q];
            atomicAdd(&olds[q][l31], gs * accO0[r]);
            atomicAdd(&olds[q][32 + l31], gs * accO1[r]);
        }
    }

    __syncthreads();

    // ---- store (valid tokens only) ----
    {
        int q = tid >> 3, dpart = (tid & 7) * 8;
        int pos = qb * BS + q;
        if (pos < len) {
            float* op = out + (((size_t)(off0 + pos)) * HH + h) * DD + dpart;
            *(float4*)op = *(float4*)&olds[q][dpart];
            *(float4*)(op + 4) = *(float4*)&olds[q][dpart + 4];
        }
    }
}

extern "C" void kernel_launch(void* const* d_in, const int* in_sizes, int n_in,
                              void* d_out, int out_size, void* d_ws, size_t ws_size,
                              hipStream_t stream) {
    const float* pq = (const float*)d_in[4];
    const float* pk = (const float*)d_in[5];
    const float* pv = (const float*)d_in[6];
    const int* xoff = (const int*)d_in[7];
    const float* gw = (const float*)d_in[8];
    float* out = (float*)d_out;

    float* kc = (float*)d_ws;                                  // [B][NB][H][D]
    float* vc = kc + (size_t)BB * NB * HH * DD;                // [B][NB][H][D]

    cmp_mean_kernel<<<BB * NB * HH / 4, 256, 0, stream>>>(pk, pv, kc, vc);
    bsa_mfma_kernel<<<BB * HH * NB, 256, 0, stream>>>(pq, pk, pv, kc, vc, gw, xoff, out);
}

// Round 4
// 173.804 us; speedup vs baseline: 1.0622x; 1.0622x over previous
//
#include <hip/hip_runtime.h>
#include <math.h>
#include <stdint.h>

#define BB 4
#define NN 1024
#define HH 8
#define DD 64
#define BS 32
#define NB 32   // NN/BS
#define SS 16   // BLOCK_COUNTS

typedef __attribute__((ext_vector_type(8)))  short bf16x8;
typedef __attribute__((ext_vector_type(16))) float f32x16;
typedef __attribute__((ext_vector_type(2)))  int   int2v;

union FragU { bf16x8 h; uint32_t u[4]; };

#define ZERO16 {0.f,0.f,0.f,0.f,0.f,0.f,0.f,0.f,0.f,0.f,0.f,0.f,0.f,0.f,0.f,0.f}

__device__ __forceinline__ uint32_t cvt_pk_bf16(float lo, float hi) {
    uint32_t r;
    asm("v_cvt_pk_bf16_f32 %0, %1, %2" : "=v"(r) : "v"(lo), "v"(hi));
    return r;
}

__device__ __forceinline__ uint16_t bf16_rne(float x) {
    uint32_t fb = __float_as_uint(x);
    return (uint16_t)((fb + 0x7fffu + ((fb >> 16) & 1u)) >> 16);
}

__device__ __forceinline__ float silu_f(float x) {
    return __fdividef(x, 1.f + __expf(-x));
}

// Prepass: one block per (b,h,cmp-block of 32 tokens).
//  Kb : bf16 [b][h][n][d]        (head-major K, MFMA A-fragment friendly)
//  Vt : bf16 [b][h][d][n]        (transposed V, contiguous B-fragment loads)
//  kc : f32  [b][h][blk][d]      (block-mean K, f32 for exact selection)
//  vct: bf16 [b][h][d][blk]      (block-mean V, transposed)
__global__ __launch_bounds__(256) void prep_kernel(
    const float* __restrict__ pk, const float* __restrict__ pv,
    uint16_t* __restrict__ Kb, uint16_t* __restrict__ Vt,
    float* __restrict__ kc, uint16_t* __restrict__ vct)
{
    __shared__ float klds[32][65];
    __shared__ float vlds[32][65];
    const int t = threadIdx.x;
    const int blk = blockIdx.x & 31;
    const int h = (blockIdx.x >> 5) & 7;
    const int b = blockIdx.x >> 8;
    const int bh = b * 8 + h;

    const int r = t >> 3;            // token row 0..31
    const int dg = (t & 7) * 8;      // d group
    size_t sbase = (((size_t)(b * NN + blk * BS + r)) * HH + h) * DD + dg;
    float4 ka = *(const float4*)(pk + sbase);
    float4 kb4 = *(const float4*)(pk + sbase + 4);
    float4 va = *(const float4*)(pv + sbase);
    float4 vb4 = *(const float4*)(pv + sbase + 4);

    FragU kf;
    kf.u[0] = cvt_pk_bf16(ka.x, ka.y);  kf.u[1] = cvt_pk_bf16(ka.z, ka.w);
    kf.u[2] = cvt_pk_bf16(kb4.x, kb4.y); kf.u[3] = cvt_pk_bf16(kb4.z, kb4.w);
    *(bf16x8*)(Kb + (((size_t)bh * NN) + blk * BS + r) * DD + dg) = kf.h;

    *(float4*)&klds[r][dg] = ka;  *(float4*)&klds[r][dg + 4] = kb4;
    *(float4*)&vlds[r][dg] = va;  *(float4*)&vlds[r][dg + 4] = vb4;
    __syncthreads();

    if (t < 64) {                    // wave 0: kc (f32 block-mean K)
        float s = 0.f;
        #pragma unroll
        for (int j = 0; j < 32; ++j) s += klds[j][t];
        kc[((size_t)bh * NB + blk) * DD + t] = s * (1.f / BS);
    } else if (t < 128) {            // wave 1: vct (bf16 block-mean V, transposed)
        int d = t - 64;
        float s = 0.f;
        #pragma unroll
        for (int j = 0; j < 32; ++j) s += vlds[j][d];
        vct[((size_t)bh * DD + d) * NB + blk] = bf16_rne(s * (1.f / BS));
    }

    // all threads: V transpose -> Vt
    {
        int d = t >> 2, ng = (t & 3) * 8;
        float p0 = vlds[ng + 0][d], p1 = vlds[ng + 1][d];
        float p2 = vlds[ng + 2][d], p3 = vlds[ng + 3][d];
        float p4 = vlds[ng + 4][d], p5 = vlds[ng + 5][d];
        float p6 = vlds[ng + 6][d], p7 = vlds[ng + 7][d];
        FragU vf;
        vf.u[0] = cvt_pk_bf16(p0, p1); vf.u[1] = cvt_pk_bf16(p2, p3);
        vf.u[2] = cvt_pk_bf16(p4, p5); vf.u[3] = cvt_pk_bf16(p6, p7);
        *(bf16x8*)(Vt + ((size_t)bh * DD + d) * NN + blk * BS + ng) = vf.h;
    }
}

// One workgroup (4 waves) per (b, h, q_block) tile of 32 queries.
// bid&7 = h  => each XCD owns one head (balanced: same work per head-sum over b).
__global__ __launch_bounds__(256, 4) void bsa_mfma_kernel(
    const float* __restrict__ pq, const uint16_t* __restrict__ Kb,
    const uint16_t* __restrict__ Vt, const float* __restrict__ kc,
    const uint16_t* __restrict__ vct, const float* __restrict__ gw,
    const int* __restrict__ xoff, float* __restrict__ out)
{
    __shared__ float qlds[32][64];                       // 8 KB
    __shared__ __align__(16) uint16_t pcmp[32][40];      // 2.5 KB
    __shared__ uint32_t selmask[32];
    __shared__ float gateC[32], gateS[32];
    __shared__ float olds[32][64];                       // 8 KB accumulation slab

    const int tid = threadIdx.x;
    const int lane = tid & 63;
    const int w = tid >> 6;
    const int l31 = lane & 31;
    const int hi = lane >> 5;

    const int bid = blockIdx.x;
    const int h = bid & 7;
    const int rem = bid >> 3;
    const int qb = rem & 31;
    const int b = rem >> 5;
    const int bh = b * 8 + h;

    const int off0 = xoff[b];
    const int len = xoff[b + 1] - off0;
    if (qb * BS >= len) return;              // fully-padded tile (uniform)

    // ---- zero accumulation slab ----
    {
        int q = tid >> 3, d = (tid & 7) * 8;
        *(float4*)&olds[q][d] = make_float4(0.f, 0.f, 0.f, 0.f);
        *(float4*)&olds[q][d + 4] = make_float4(0.f, 0.f, 0.f, 0.f);
    }

    // ---- cooperative load of Q tile (f32) for selection/gates ----
    {
        int q = tid >> 3, part = (tid & 7) * 8;
        const float* src = pq + (((size_t)(b * NN + qb * BS + q)) * HH + h) * DD + part;
        *(float4*)&qlds[q][part] = *(const float4*)src;
        *(float4*)&qlds[q][part + 4] = *(const float4*)(src + 4);
    }

    // ---- Q B-fragments (bf16) direct from global: lane = query l31 ----
    FragU qf[4];
    {
        const float* qrow = pq + (((size_t)(b * NN + qb * BS + l31)) * HH + h) * DD;
        #pragma unroll
        for (int t = 0; t < 4; ++t) {
            const float* qp = qrow + t * 16 + hi * 8;
            float4 x = *(const float4*)qp;
            float4 y = *(const float4*)(qp + 4);
            qf[t].u[0] = cvt_pk_bf16(x.x, x.y);
            qf[t].u[1] = cvt_pk_bf16(x.z, x.w);
            qf[t].u[2] = cvt_pk_bf16(y.x, y.y);
            qf[t].u[3] = cvt_pk_bf16(y.z, y.w);
        }
    }

    // ---- compressed-K fragments for selection dots: lane = (blk=l31, half=hi) ----
    float4 kcv[8];
    {
        const float* kcrow = kc + ((size_t)bh * NB + l31) * DD + hi * 32;
        #pragma unroll
        for (int i = 0; i < 8; ++i) kcv[i] = *(const float4*)(kcrow + i * 4);
    }

    __syncthreads();   // qlds + olds ready

    // ---- selection + gates: wave w handles queries w*8 .. w*8+7 ----
    for (int j = 0; j < 8; ++j) {
        int q = w * 8 + j;
        const float* qv = qlds[q];
        const float* qh = qv + hi * 32;
        float part = 0.f;
        #pragma unroll
        for (int i = 0; i < 8; ++i) {
            float4 qq = *(const float4*)(qh + i * 4);
            part += qq.x * kcv[i].x + qq.y * kcv[i].y + qq.z * kcv[i].z + qq.w * kcv[i].w;
        }
        float s = (part + __shfl_xor(part, 32)) * 0.125f;
        float p = (l31 <= qb) ? silu_f(s) : 0.f;
        if (lane < 32) pcmp[q][l31] = bf16_rne(p);
        // top-16 mask (fp32 scores, index tie-break == jax.lax.top_k)
        uint32_t m;
        if (qb >= SS) {
            float vsel = (l31 <= qb) ? s : -INFINITY;
            int rank = 0;
            #pragma unroll
            for (int off = 1; off < 32; ++off) {
                float o = __shfl_xor(vsel, off);
                int oi = l31 ^ off;
                rank += (o > vsel || (o == vsel && oi < l31)) ? 1 : 0;
            }
            m = (uint32_t)(__ballot(rank < SS) & 0xffffffffu);
        } else {
            m = (1u << (qb + 1)) - 1u;
        }
        if (lane == 0) selmask[q] = m;
        // gates
        float qd = qv[lane];
        float g0 = qd * gw[(h * DD + lane) * 3 + 0];
        float g1 = qd * gw[(h * DD + lane) * 3 + 1];
        #pragma unroll
        for (int off = 32; off; off >>= 1) {
            g0 += __shfl_xor(g0, off);
            g1 += __shfl_xor(g1, off);
        }
        if (lane == 0) {
            gateC[q] = __frcp_rn(1.f + __expf(-g0));
            gateS[q] = __frcp_rn(1.f + __expf(-g1));
        }
    }

    __syncthreads();   // pcmp, selmask, gates ready

    const uint32_t mymask = selmask[l31];   // per-lane: mask for query l31
    uint32_t tmask = mymask;                 // tile union of selected blocks
    #pragma unroll
    for (int off = 1; off < 32; off <<= 1) tmask |= __shfl_xor(tmask, off);

    // ---- wave 3: compressed branch o_cmp = P_cmp · v_cmp via MFMA (gated) ----
    if (w == 3) {
        f32x16 c0 = ZERO16, c1 = ZERO16;
        #pragma unroll
        for (int s = 0; s < 2; ++s) {
            FragU pa;
            pa.h = *(const bf16x8*)&pcmp[l31][s * 16 + hi * 8];
            #pragma unroll
            for (int dh = 0; dh < 2; ++dh) {
                FragU vb;
                vb.h = *(const bf16x8*)(vct + ((size_t)bh * DD + dh * 32 + l31) * NB + s * 16 + hi * 8);
                if (dh == 0) c0 = __builtin_amdgcn_mfma_f32_32x32x16_bf16(pa.h, vb.h, c0, 0, 0, 0);
                else         c1 = __builtin_amdgcn_mfma_f32_32x32x16_bf16(pa.h, vb.h, c1, 0, 0, 0);
            }
        }
        #pragma unroll
        for (int r = 0; r < 16; ++r) {
            int q = (r & 3) + 8 * (r >> 2) + 4 * hi;
            float gc = gateC[q];
            atomicAdd(&olds[q][l31], gc * c0[r]);
            atomicAdd(&olds[q][32 + l31], gc * c1[r]);
        }
    }

    // ---- main loop: waves round-robin over union-selected key blocks ----
    f32x16 accO0 = ZERO16, accO1 = ZERO16;
    bool any = false;
    const int qpos = qb * BS + l31;
    {
        uint32_t m = tmask;
        int bcnt = 0;
        while (m) {
            int kb = __builtin_ctz(m); m &= m - 1;
            if (((bcnt++) & 3) != w) continue;
            any = true;
            // S^T = K_blk · Q^T  (4 mfma over d), K from pre-converted bf16
            f32x16 accS = ZERO16;
            const uint16_t* krow = Kb + (((size_t)bh * NN) + kb * BS + l31) * DD;
            #pragma unroll
            for (int t = 0; t < 4; ++t) {
                FragU kf;
                kf.h = *(const bf16x8*)(krow + t * 16 + hi * 8);
                accS = __builtin_amdgcn_mfma_f32_32x32x16_bf16(kf.h, qf[t].h, accS, 0, 0, 0);
            }
            // mask + silu (lane holds q = l31; rows are keys)
            const bool selbit = (mymask >> kb) & 1;
            const bool notdiag = kb < qb;
            float pr[16];
            #pragma unroll
            for (int r = 0; r < 16; ++r) {
                int key = (r & 3) + 8 * (r >> 2) + 4 * hi;
                int kpos = kb * BS + key;
                float s = accS[r] * 0.125f;
                bool ok = selbit && (notdiag || kpos <= qpos);
                pr[r] = ok ? silu_f(s) : 0.f;
            }
            // P -> A-operand layout: cvt_pk pairs + permlane32 swaps
            uint32_t wv[8];
            #pragma unroll
            for (int i = 0; i < 8; ++i) wv[i] = cvt_pk_bf16(pr[2 * i], pr[2 * i + 1]);
            int2v e0 = __builtin_amdgcn_permlane32_swap(wv[0], wv[2], false, false);
            int2v e1 = __builtin_amdgcn_permlane32_swap(wv[1], wv[3], false, false);
            int2v e2 = __builtin_amdgcn_permlane32_swap(wv[4], wv[6], false, false);
            int2v e3 = __builtin_amdgcn_permlane32_swap(wv[5], wv[7], false, false);
            FragU a0, a1;
            a0.u[0] = e0[0]; a0.u[1] = e1[0]; a0.u[2] = e0[1]; a0.u[3] = e1[1];
            a1.u[0] = e2[0]; a1.u[1] = e3[0]; a1.u[2] = e2[1]; a1.u[3] = e3[1];
            // PV: O += P · V, V fragments are single contiguous bf16x8 loads
            #pragma unroll
            for (int s = 0; s < 2; ++s) {
                const FragU& pa = s ? a1 : a0;
                #pragma unroll
                for (int dh = 0; dh < 2; ++dh) {
                    FragU vb;
                    vb.h = *(const bf16x8*)(Vt + ((size_t)bh * DD + dh * 32 + l31) * NN + kb * BS + s * 16 + hi * 8);
                    if (dh == 0) accO0 = __builtin_amdgcn_mfma_f32_32x32x16_bf16(pa.h, vb.h, accO0, 0, 0, 0);
                    else         accO1 = __builtin_amdgcn_mfma_f32_32x32x16_bf16(pa.h, vb.h, accO1, 0, 0, 0);
                }
            }
        }
    }

    // ---- gated accumulation of selected-branch partials ----
    if (any) {
        #pragma unroll
        for (int r = 0; r < 16; ++r) {
            int q = (r & 3) + 8 * (r >> 2) + 4 * hi;
            float gs = gateS[q];
            atomicAdd(&olds[q][l31], gs * accO0[r]);
            atomicAdd(&olds[q][32 + l31], gs * accO1[r]);
        }
    }

    __syncthreads();

    // ---- store (valid tokens only) ----
    {
        int q = tid >> 3, dpart = (tid & 7) * 8;
        int pos = qb * BS + q;
        if (pos < len) {
            float* op = out + (((size_t)(off0 + pos)) * HH + h) * DD + dpart;
            *(float4*)op = *(float4*)&olds[q][dpart];
            *(float4*)(op + 4) = *(float4*)&olds[q][dpart + 4];
        }
    }
}

extern "C" void kernel_launch(void* const* d_in, const int* in_sizes, int n_in,
                              void* d_out, int out_size, void* d_ws, size_t ws_size,
                              hipStream_t stream) {
    const float* pq = (const float*)d_in[4];
    const float* pk = (const float*)d_in[5];
    const float* pv = (const float*)d_in[6];
    const int* xoff = (const int*)d_in[7];
    const float* gw = (const float*)d_in[8];
    float* out = (float*)d_out;

    // workspace layout: Kb 4MB | Vt 4MB | kc 256KB | vct 128KB  (~8.4 MB)
    uint16_t* Kb = (uint16_t*)d_ws;
    uint16_t* Vt = Kb + (size_t)BB * HH * NN * DD;
    float* kc = (float*)(Vt + (size_t)BB * HH * NN * DD);
    uint16_t* vct = (uint16_t*)(kc + (size_t)BB * HH * NB * DD);

    prep_kernel<<<BB * HH * NB, 256, 0, stream>>>(pk, pv, Kb, Vt, kc, vct);
    bsa_mfma_kernel<<<BB * HH * NB, 256, 0, stream>>>(pq, Kb, Vt, kc, vct, gw, xoff, out);
}